// Round 3
// baseline (3081.019 us; speedup 1.0000x reference)
//
#include <hip/hip_runtime.h>
#include <math.h>

#define DIM   4096
#define NITER 20
#define EPSF  1e-10f
#define NB    512          // 2 blocks per CU
#define NT    1024
#define RPB   8            // rows per block
#define NRG   16           // fallback path

// ================= two-level grid barrier (agent scope, cross-XCD safe) ==========
// bar layout (64B-spaced slots): gen@0, root@16, cnt[i]@32+16i (i<16)
__device__ __forceinline__ void gridbarrier(unsigned* bar, int b) {
    __syncthreads();
    if (threadIdx.x == 0) {
        unsigned* gen  = bar;
        unsigned* root = bar + 16;
        unsigned* cnt  = bar + 32 + 16 * (b & 15);
        unsigned g = __hip_atomic_load(gen, __ATOMIC_RELAXED, __HIP_MEMORY_SCOPE_AGENT);
        bool winner = false;
        unsigned a = __hip_atomic_fetch_add(cnt, 1u, __ATOMIC_ACQ_REL, __HIP_MEMORY_SCOPE_AGENT);
        if (a == 31u) {  // 512 blocks / 16 counters = 32 arrivals each
            unsigned a2 = __hip_atomic_fetch_add(root, 1u, __ATOMIC_ACQ_REL, __HIP_MEMORY_SCOPE_AGENT);
            if (a2 == 15u) {
                __hip_atomic_store(root, 0u, __ATOMIC_RELAXED, __HIP_MEMORY_SCOPE_AGENT);
                for (int i = 0; i < 16; ++i)
                    __hip_atomic_store(bar + 32 + 16 * i, 0u, __ATOMIC_RELAXED, __HIP_MEMORY_SCOPE_AGENT);
                __hip_atomic_fetch_add(gen, 1u, __ATOMIC_RELEASE, __HIP_MEMORY_SCOPE_AGENT);
                winner = true;
            }
        }
        if (!winner) {
            while (__hip_atomic_load(gen, __ATOMIC_ACQUIRE, __HIP_MEMORY_SCOPE_AGENT) == g)
                __builtin_amdgcn_s_sleep(1);
        }
    }
    __syncthreads();
}

__global__ void zero_bar(unsigned* bar) {
    if (threadIdx.x < 512) bar[threadIdx.x] = 0u;
}

// ================= persistent Sinkhorn: matrix in registers, 32 VGPR/thread ======
__global__ __launch_bounds__(NT, 8) void sinkhorn_persistent(
        const float* __restrict__ logits, const float* __restrict__ noise,
        float* __restrict__ out, float* __restrict__ c, unsigned* __restrict__ bar) {
    __shared__ float wred[RPB][17];
    __shared__ float Mbc[RPB];
    __shared__ float rbc[RPB];

    const int t = threadIdx.x;
    const int b = blockIdx.x;
    const int wave = t >> 6, lane = t & 63;
    const int g0 = b * RPB;                // block's first row
    float* part = out;                     // first 8 MiB of out = partial scratch

    // ---- init: L0 into registers (read HBM once, never again) ----
    float4 v[RPB];
#pragma unroll
    for (int r = 0; r < RPB; ++r) {
        const float4 l = *(const float4*)(logits + (size_t)(g0 + r) * DIM + 4 * t);
        const float4 u = *(const float4*)(noise  + (size_t)(g0 + r) * DIM + 4 * t);
        v[r].x = l.x - __logf(-__logf(u.x + EPSF) + EPSF);
        v[r].y = l.y - __logf(-__logf(u.y + EPSF) + EPSF);
        v[r].z = l.z - __logf(-__logf(u.z + EPSF) + EPSF);
        v[r].w = l.w - __logf(-__logf(u.w + EPSF) + EPSF);
    }
    float4 cc = make_float4(0.f, 0.f, 0.f, 0.f);

    for (int it = 0; it < NITER; ++it) {
        // ---------- row LSE (block-local): rbc[r] = LSE_j(v - c) ----------
#pragma unroll
        for (int r = 0; r < RPB; ++r) {
            float m = fmaxf(fmaxf(v[r].x - cc.x, v[r].y - cc.y),
                            fmaxf(v[r].z - cc.z, v[r].w - cc.w));
#pragma unroll
            for (int o = 32; o > 0; o >>= 1) m = fmaxf(m, __shfl_down(m, o, 64));
            if (lane == 0) wred[r][wave] = m;
        }
        __syncthreads();
        if (t < RPB) {
            float M = wred[t][0];
#pragma unroll
            for (int i = 1; i < 16; ++i) M = fmaxf(M, wred[t][i]);
            Mbc[t] = M;
        }
        __syncthreads();
#pragma unroll
        for (int r = 0; r < RPB; ++r) {
            const float M = Mbc[r];
            float s = __expf(v[r].x - cc.x - M) + __expf(v[r].y - cc.y - M)
                    + __expf(v[r].z - cc.z - M) + __expf(v[r].w - cc.w - M);
#pragma unroll
            for (int o = 32; o > 0; o >>= 1) s += __shfl_down(s, o, 64);
            if (lane == 0) wred[r][wave] = s;
        }
        __syncthreads();
        if (t < RPB) {
            float S = 0.f;
#pragma unroll
            for (int i = 0; i < 16; ++i) S += wred[t][i];
            rbc[t] = Mbc[t] + __logf(S);
        }
        __syncthreads();

        // ---------- col partial LSE (thread-local over 8 rows) ----------
        float4 pl;
#define COL_PARTIAL(comp, ccc, dst)                                      \
        {                                                                \
            float m = v[0].comp - rbc[0];                                \
            _Pragma("unroll")                                            \
            for (int r2 = 1; r2 < RPB; ++r2)                             \
                m = fmaxf(m, v[r2].comp - rbc[r2]);                      \
            float s = 0.f;                                               \
            _Pragma("unroll")                                            \
            for (int r2 = 0; r2 < RPB; ++r2)                             \
                s += __expf(v[r2].comp - rbc[r2] - m);                   \
            dst = m + __logf(s);                                         \
        }
        COL_PARTIAL(x, cc.x, pl.x)
        COL_PARTIAL(y, cc.y, pl.y)
        COL_PARTIAL(z, cc.z, pl.z)
        COL_PARTIAL(w, cc.w, pl.w)
#undef COL_PARTIAL
        *(float4*)(part + (size_t)b * DIM + 4 * t) = pl;

        gridbarrier(bar, b);

        // ---------- combine: waves 0..7 -> c[8b + wave] over 512 partials ----------
        if (wave < RPB) {
            const int jj = g0 + wave;
            float m = -INFINITY;
            float p[8];
#pragma unroll
            for (int k = 0; k < 8; ++k) {
                p[k] = part[(size_t)(lane + 64 * k) * DIM + jj];
                m = fmaxf(m, p[k]);
            }
#pragma unroll
            for (int o = 1; o < 64; o <<= 1) m = fmaxf(m, __shfl_xor(m, o, 64));
            float s = 0.f;
#pragma unroll
            for (int k = 0; k < 8; ++k) s += __expf(p[k] - m);
#pragma unroll
            for (int o = 1; o < 64; o <<= 1) s += __shfl_xor(s, o, 64);
            if (lane == 0) c[jj] = m + __logf(s);
        }

        gridbarrier(bar, b);

        cc = *(const float4*)(c + 4 * t);   // fresh column offsets for next iter
    }

    // ---------- final: out = exp(L0 - r - c) ----------
#pragma unroll
    for (int r = 0; r < RPB; ++r) {
        float4 o;
        o.x = __expf(v[r].x - rbc[r] - cc.x);
        o.y = __expf(v[r].y - rbc[r] - cc.y);
        o.z = __expf(v[r].z - rbc[r] - cc.z);
        o.w = __expf(v[r].w - rbc[r] - cc.w);
        *(float4*)(out + (size_t)(g0 + r) * DIM + 4 * t) = o;
    }
}

// =================== fallback pipeline (round-1, known-good) =====================
__device__ __forceinline__ float waveMaxF(float v) {
#pragma unroll
    for (int o = 32; o > 0; o >>= 1) v = fmaxf(v, __shfl_down(v, o, 64));
    return v;
}
__device__ __forceinline__ float waveSumF(float v) {
#pragma unroll
    for (int o = 32; o > 0; o >>= 1) v += __shfl_down(v, o, 64);
    return v;
}

__global__ __launch_bounds__(256) void init_k(const float* __restrict__ logits,
                                              const float* __restrict__ noise,
                                              float* __restrict__ L0,
                                              float* __restrict__ c) {
    int idx = blockIdx.x * blockDim.x + threadIdx.x;
    int stride = gridDim.x * blockDim.x;
    const float4* l4 = (const float4*)logits;
    const float4* n4 = (const float4*)noise;
    float4* o4 = (float4*)L0;
    for (int p = idx; p < DIM * DIM / 4; p += stride) {
        float4 l = l4[p];
        float4 u = n4[p];
        float4 o;
        o.x = l.x - __logf(-__logf(u.x + EPSF) + EPSF);
        o.y = l.y - __logf(-__logf(u.y + EPSF) + EPSF);
        o.z = l.z - __logf(-__logf(u.z + EPSF) + EPSF);
        o.w = l.w - __logf(-__logf(u.w + EPSF) + EPSF);
        o4[p] = o;
    }
    if (idx < DIM) c[idx] = 0.0f;
}

__global__ __launch_bounds__(256) void row_lse(const float* __restrict__ L0,
                                               const float* __restrict__ c,
                                               float* __restrict__ r) {
    __shared__ float red[8];
    const int row = blockIdx.x;
    const int t = threadIdx.x;
    const float4* a4 = (const float4*)(L0 + (size_t)row * DIM);
    const float4* c4 = (const float4*)c;
    float v[16];
    float m = -INFINITY;
#pragma unroll
    for (int k = 0; k < 4; ++k) {
        float4 a  = a4[t + k * 256];
        float4 cc = c4[t + k * 256];
        v[4 * k + 0] = a.x - cc.x;
        v[4 * k + 1] = a.y - cc.y;
        v[4 * k + 2] = a.z - cc.z;
        v[4 * k + 3] = a.w - cc.w;
        m = fmaxf(m, fmaxf(fmaxf(v[4 * k], v[4 * k + 1]), fmaxf(v[4 * k + 2], v[4 * k + 3])));
    }
    m = waveMaxF(m);
    const int lane = t & 63, wid = t >> 6;
    if (lane == 0) red[wid] = m;
    __syncthreads();
    const float bm = fmaxf(fmaxf(red[0], red[1]), fmaxf(red[2], red[3]));
    float s = 0.0f;
#pragma unroll
    for (int q = 0; q < 16; ++q) s += __expf(v[q] - bm);
    s = waveSumF(s);
    if (lane == 0) red[4 + wid] = s;
    __syncthreads();
    if (t == 0) r[row] = bm + __logf(red[4] + red[5] + red[6] + red[7]);
}

__global__ __launch_bounds__(1024) void col_partial(const float* __restrict__ L0,
                                                    const float* __restrict__ r,
                                                    float2* __restrict__ part) {
    __shared__ float sr[256];
    __shared__ float smm[1024];
    __shared__ float sms[1024];
    const int g = blockIdx.x, h = blockIdx.y;
    const int tc = threadIdx.x & 255;
    const int ln = threadIdx.x >> 8;
    if (threadIdx.x < 256) sr[threadIdx.x] = r[h * 256 + threadIdx.x];
    __syncthreads();
    const int j = g * 256 + tc;
    float m = -INFINITY, s = 0.0f;
#pragma unroll 4
    for (int k = 0; k < 64; ++k) {
        int ii = k * 4 + ln;
        float v = L0[(size_t)(h * 256 + ii) * DIM + j] - sr[ii];
        float nm = fmaxf(m, v);
        s = s * __expf(m - nm) + __expf(v - nm);
        m = nm;
    }
    smm[threadIdx.x] = m;
    sms[threadIdx.x] = s;
    __syncthreads();
    if (threadIdx.x < 256) {
        float m0 = smm[tc], m1 = smm[tc + 256], m2 = smm[tc + 512], m3 = smm[tc + 768];
        float M = fmaxf(fmaxf(m0, m1), fmaxf(m2, m3));
        float S = sms[tc] * __expf(m0 - M) + sms[tc + 256] * __expf(m1 - M) +
                  sms[tc + 512] * __expf(m2 - M) + sms[tc + 768] * __expf(m3 - M);
        part[h * DIM + j] = make_float2(M, S);
    }
}

__global__ __launch_bounds__(256) void col_combine(const float2* __restrict__ part,
                                                   float* __restrict__ c) {
    int j = blockIdx.x * 256 + threadIdx.x;
    float pm[NRG], ps[NRG];
    float M = -INFINITY;
#pragma unroll
    for (int h = 0; h < NRG; ++h) {
        float2 p = part[h * DIM + j];
        pm[h] = p.x; ps[h] = p.y;
        M = fmaxf(M, p.x);
    }
    float S = 0.0f;
#pragma unroll
    for (int h = 0; h < NRG; ++h) S += ps[h] * __expf(pm[h] - M);
    c[j] = M + __logf(S);
}

__global__ __launch_bounds__(256) void final_exp(float* __restrict__ L0,
                                                 const float* __restrict__ r,
                                                 const float* __restrict__ c) {
    const float4* c4 = (const float4*)c;
    float4* a4 = (float4*)L0;
    int idx = blockIdx.x * blockDim.x + threadIdx.x;
    int stride = gridDim.x * blockDim.x;
    for (int p = idx; p < DIM * DIM / 4; p += stride) {
        int i  = p >> 10;
        int j4 = p & 1023;
        float4 a = a4[p];
        float rrv = r[i];
        float4 ccv = c4[j4];
        a.x = __expf(a.x - rrv - ccv.x);
        a.y = __expf(a.y - rrv - ccv.y);
        a.z = __expf(a.z - rrv - ccv.z);
        a.w = __expf(a.w - rrv - ccv.w);
        a4[p] = a;
    }
}

// ====================================== launch ===================================
extern "C" void kernel_launch(void* const* d_in, const int* in_sizes, int n_in,
                              void* d_out, int out_size, void* d_ws, size_t ws_size,
                              hipStream_t stream) {
    const float* logits = (const float*)d_in[0];
    const float* noise  = (const float*)d_in[1];
    float* out = (float*)d_out;
    float* c   = (float*)d_ws;                          // 16 KiB
    unsigned* bar = (unsigned*)((char*)d_ws + 16384);   // 2 KiB barrier state

    zero_bar<<<1, 512, 0, stream>>>(bar);
    void* args[] = { (void*)&logits, (void*)&noise, (void*)&out, (void*)&c, (void*)&bar };
    hipError_t err = hipLaunchCooperativeKernel((const void*)sinkhorn_persistent,
                                                dim3(NB), dim3(NT), args, 0, stream);
    if (err != hipSuccess) {
        // fallback: round-1 multi-kernel pipeline (known-good)
        float* ws = (float*)d_ws;
        float*  r    = ws;
        float*  cf   = ws + DIM;
        float2* part = (float2*)(ws + 2 * DIM);
        init_k<<<4096, 256, 0, stream>>>(logits, noise, out, cf);
        for (int t = 0; t < NITER; ++t) {
            row_lse<<<DIM, 256, 0, stream>>>(out, cf, r);
            col_partial<<<dim3(16, 16), 1024, 0, stream>>>(out, r, part);
            col_combine<<<16, 256, 0, stream>>>(part, cf);
        }
        final_exp<<<4096, 256, 0, stream>>>(out, r, cf);
    }
}

// Round 4
// 1602.825 us; speedup vs baseline: 1.9222x; 1.9222x over previous
//
#include <hip/hip_runtime.h>
#include <math.h>

#define DIM   4096
#define NITER 20
#define EPSF  1e-10f
#define NB    256
#define NT    1024
#define RPB   16           // rows per block
#define NRG   16           // fallback path

typedef __attribute__((ext_vector_type(4))) _Float16 half4;

// ================= two-level grid barrier (agent scope, cross-XCD safe) ==========
// Proven correct in rounds 2-3. bar layout (64B slots): gen@0, root@16, cnt[i]@32+16i
__device__ __forceinline__ void gridbarrier(unsigned* bar, int b) {
    __syncthreads();
    if (threadIdx.x == 0) {
        unsigned* gen  = bar;
        unsigned* root = bar + 16;
        unsigned* cnt  = bar + 32 + 16 * (b & 7);
        unsigned g = __hip_atomic_load(gen, __ATOMIC_RELAXED, __HIP_MEMORY_SCOPE_AGENT);
        bool winner = false;
        unsigned a = __hip_atomic_fetch_add(cnt, 1u, __ATOMIC_ACQ_REL, __HIP_MEMORY_SCOPE_AGENT);
        if (a == 31u) {  // 256 blocks / 8 counters = 32 arrivals each
            unsigned a2 = __hip_atomic_fetch_add(root, 1u, __ATOMIC_ACQ_REL, __HIP_MEMORY_SCOPE_AGENT);
            if (a2 == 7u) {
                __hip_atomic_store(root, 0u, __ATOMIC_RELAXED, __HIP_MEMORY_SCOPE_AGENT);
                for (int i = 0; i < 8; ++i)
                    __hip_atomic_store(bar + 32 + 16 * i, 0u, __ATOMIC_RELAXED, __HIP_MEMORY_SCOPE_AGENT);
                __hip_atomic_fetch_add(gen, 1u, __ATOMIC_RELEASE, __HIP_MEMORY_SCOPE_AGENT);
                winner = true;
            }
        }
        if (!winner) {
            while (__hip_atomic_load(gen, __ATOMIC_ACQUIRE, __HIP_MEMORY_SCOPE_AGENT) == g)
                __builtin_amdgcn_s_sleep(1);
        }
    }
    __syncthreads();
}

__global__ void zero_bar(unsigned* bar) {
    if (threadIdx.x < 256) bar[threadIdx.x] = 0u;
}

// ============ persistent Sinkhorn: matrix lives in LDS as fp16 ===================
__global__ __launch_bounds__(NT, 4) void sinkhorn_lds(
        const float* __restrict__ logits, const float* __restrict__ noise,
        float* __restrict__ out, float* __restrict__ cg, unsigned* __restrict__ bar) {
    __shared__ _Float16 lm[RPB][DIM];   // 128 KiB: block's 16 rows of L0
    __shared__ float    lc[DIM];        //  16 KiB: local fp32 copy of c
    __shared__ float    rbc[RPB];       // row potentials

    const int t = threadIdx.x;
    const int b = blockIdx.x;
    const int wave = t >> 6, lane = t & 63;
    const int g0 = b * RPB;
    float* part = out;                  // first 4 MiB of out = partial scratch

    // ---- init: L0 = logits + gumbel(noise) -> fp16 in LDS (HBM read once) ----
#pragma unroll
    for (int r = 0; r < RPB; ++r) {
        const float4 l = *(const float4*)(logits + (size_t)(g0 + r) * DIM + 4 * t);
        const float4 u = *(const float4*)(noise  + (size_t)(g0 + r) * DIM + 4 * t);
        half4 h;
        h.x = (_Float16)(l.x - __logf(-__logf(u.x + EPSF) + EPSF));
        h.y = (_Float16)(l.y - __logf(-__logf(u.y + EPSF) + EPSF));
        h.z = (_Float16)(l.z - __logf(-__logf(u.z + EPSF) + EPSF));
        h.w = (_Float16)(l.w - __logf(-__logf(u.w + EPSF) + EPSF));
        *(half4*)&lm[r][4 * t] = h;
    }
    *(float4*)&lc[4 * t] = make_float4(0.f, 0.f, 0.f, 0.f);
    __syncthreads();

    for (int it = 0; it < NITER; ++it) {
        // ---------- row LSE: wave w <-> row w, exact two-pass, shfl butterfly ----
        {
            float m = -1e30f;
#pragma unroll
            for (int k = 0; k < 16; ++k) {
                const int col = (k * 64 + lane) * 4;
                const half4  h  = *(const half4*)&lm[wave][col];
                const float4 c4 = *(const float4*)&lc[col];
                m = fmaxf(m, fmaxf(fmaxf((float)h.x - c4.x, (float)h.y - c4.y),
                                   fmaxf((float)h.z - c4.z, (float)h.w - c4.w)));
            }
#pragma unroll
            for (int o = 1; o < 64; o <<= 1) m = fmaxf(m, __shfl_xor(m, o, 64));
            float s = 0.f;
#pragma unroll
            for (int k = 0; k < 16; ++k) {
                const int col = (k * 64 + lane) * 4;
                const half4  h  = *(const half4*)&lm[wave][col];
                const float4 c4 = *(const float4*)&lc[col];
                s += __expf((float)h.x - c4.x - m) + __expf((float)h.y - c4.y - m)
                   + __expf((float)h.z - c4.z - m) + __expf((float)h.w - c4.w - m);
            }
#pragma unroll
            for (int o = 1; o < 64; o <<= 1) s += __shfl_xor(s, o, 64);
            if (lane == 0) rbc[wave] = m + __logf(s);
        }
        __syncthreads();

        // ---------- col partial LSE: thread t <-> cols 4t..4t+3 over 16 rows ----
        {
            float4 mx = make_float4(-1e30f, -1e30f, -1e30f, -1e30f);
#pragma unroll
            for (int r2 = 0; r2 < RPB; ++r2) {
                const half4 h = *(const half4*)&lm[r2][4 * t];
                const float rr = rbc[r2];
                mx.x = fmaxf(mx.x, (float)h.x - rr);
                mx.y = fmaxf(mx.y, (float)h.y - rr);
                mx.z = fmaxf(mx.z, (float)h.z - rr);
                mx.w = fmaxf(mx.w, (float)h.w - rr);
            }
            float4 sm = make_float4(0.f, 0.f, 0.f, 0.f);
#pragma unroll
            for (int r2 = 0; r2 < RPB; ++r2) {
                const half4 h = *(const half4*)&lm[r2][4 * t];
                const float rr = rbc[r2];
                sm.x += __expf((float)h.x - rr - mx.x);
                sm.y += __expf((float)h.y - rr - mx.y);
                sm.z += __expf((float)h.z - rr - mx.z);
                sm.w += __expf((float)h.w - rr - mx.w);
            }
            float4 pl;
            pl.x = mx.x + __logf(sm.x);
            pl.y = mx.y + __logf(sm.y);
            pl.z = mx.z + __logf(sm.z);
            pl.w = mx.w + __logf(sm.w);
            *(float4*)(part + (size_t)b * DIM + 4 * t) = pl;
        }

        gridbarrier(bar, b);

        // ---------- combine: wave w -> c[16b + w] over 256 block partials ----
        {
            const int jj = g0 + wave;
            const float p0 = part[(size_t)(lane      ) * DIM + jj];
            const float p1 = part[(size_t)(lane +  64) * DIM + jj];
            const float p2 = part[(size_t)(lane + 128) * DIM + jj];
            const float p3 = part[(size_t)(lane + 192) * DIM + jj];
            float m = fmaxf(fmaxf(p0, p1), fmaxf(p2, p3));
#pragma unroll
            for (int o = 1; o < 64; o <<= 1) m = fmaxf(m, __shfl_xor(m, o, 64));
            float s = __expf(p0 - m) + __expf(p1 - m) + __expf(p2 - m) + __expf(p3 - m);
#pragma unroll
            for (int o = 1; o < 64; o <<= 1) s += __shfl_xor(s, o, 64);
            if (lane == 0) cg[jj] = m + __logf(s);
        }

        gridbarrier(bar, b);

        // ---------- refresh local c copy ----------
        *(float4*)&lc[4 * t] = *(const float4*)(cg + 4 * t);
        __syncthreads();
    }

    // ---------- final: out = exp(L0 - r - c) ----------
    const float4 c4f = *(const float4*)&lc[4 * t];
#pragma unroll
    for (int r = 0; r < RPB; ++r) {
        const half4 h = *(const half4*)&lm[r][4 * t];
        const float rr = rbc[r];
        float4 o;
        o.x = __expf((float)h.x - rr - c4f.x);
        o.y = __expf((float)h.y - rr - c4f.y);
        o.z = __expf((float)h.z - rr - c4f.z);
        o.w = __expf((float)h.w - rr - c4f.w);
        *(float4*)(out + (size_t)(g0 + r) * DIM + 4 * t) = o;
    }
}

// =================== fallback pipeline (round-1, known-good 769 us) ==============
__device__ __forceinline__ float waveMaxF(float v) {
#pragma unroll
    for (int o = 32; o > 0; o >>= 1) v = fmaxf(v, __shfl_down(v, o, 64));
    return v;
}
__device__ __forceinline__ float waveSumF(float v) {
#pragma unroll
    for (int o = 32; o > 0; o >>= 1) v += __shfl_down(v, o, 64);
    return v;
}

__global__ __launch_bounds__(256) void init_k(const float* __restrict__ logits,
                                              const float* __restrict__ noise,
                                              float* __restrict__ L0,
                                              float* __restrict__ c) {
    int idx = blockIdx.x * blockDim.x + threadIdx.x;
    int stride = gridDim.x * blockDim.x;
    const float4* l4 = (const float4*)logits;
    const float4* n4 = (const float4*)noise;
    float4* o4 = (float4*)L0;
    for (int p = idx; p < DIM * DIM / 4; p += stride) {
        float4 l = l4[p];
        float4 u = n4[p];
        float4 o;
        o.x = l.x - __logf(-__logf(u.x + EPSF) + EPSF);
        o.y = l.y - __logf(-__logf(u.y + EPSF) + EPSF);
        o.z = l.z - __logf(-__logf(u.z + EPSF) + EPSF);
        o.w = l.w - __logf(-__logf(u.w + EPSF) + EPSF);
        o4[p] = o;
    }
    if (idx < DIM) c[idx] = 0.0f;
}

__global__ __launch_bounds__(256) void row_lse(const float* __restrict__ L0,
                                               const float* __restrict__ c,
                                               float* __restrict__ r) {
    __shared__ float red[8];
    const int row = blockIdx.x;
    const int t = threadIdx.x;
    const float4* a4 = (const float4*)(L0 + (size_t)row * DIM);
    const float4* c4 = (const float4*)c;
    float v[16];
    float m = -INFINITY;
#pragma unroll
    for (int k = 0; k < 4; ++k) {
        float4 a  = a4[t + k * 256];
        float4 cc = c4[t + k * 256];
        v[4 * k + 0] = a.x - cc.x;
        v[4 * k + 1] = a.y - cc.y;
        v[4 * k + 2] = a.z - cc.z;
        v[4 * k + 3] = a.w - cc.w;
        m = fmaxf(m, fmaxf(fmaxf(v[4 * k], v[4 * k + 1]), fmaxf(v[4 * k + 2], v[4 * k + 3])));
    }
    m = waveMaxF(m);
    const int lane = t & 63, wid = t >> 6;
    if (lane == 0) red[wid] = m;
    __syncthreads();
    const float bm = fmaxf(fmaxf(red[0], red[1]), fmaxf(red[2], red[3]));
    float s = 0.0f;
#pragma unroll
    for (int q = 0; q < 16; ++q) s += __expf(v[q] - bm);
    s = waveSumF(s);
    if (lane == 0) red[4 + wid] = s;
    __syncthreads();
    if (t == 0) r[row] = bm + __logf(red[4] + red[5] + red[6] + red[7]);
}

__global__ __launch_bounds__(1024) void col_partial(const float* __restrict__ L0,
                                                    const float* __restrict__ r,
                                                    float2* __restrict__ part) {
    __shared__ float sr[256];
    __shared__ float smm[1024];
    __shared__ float sms[1024];
    const int g = blockIdx.x, h = blockIdx.y;
    const int tc = threadIdx.x & 255;
    const int ln = threadIdx.x >> 8;
    if (threadIdx.x < 256) sr[threadIdx.x] = r[h * 256 + threadIdx.x];
    __syncthreads();
    const int j = g * 256 + tc;
    float m = -INFINITY, s = 0.0f;
#pragma unroll 4
    for (int k = 0; k < 64; ++k) {
        int ii = k * 4 + ln;
        float v = L0[(size_t)(h * 256 + ii) * DIM + j] - sr[ii];
        float nm = fmaxf(m, v);
        s = s * __expf(m - nm) + __expf(v - nm);
        m = nm;
    }
    smm[threadIdx.x] = m;
    sms[threadIdx.x] = s;
    __syncthreads();
    if (threadIdx.x < 256) {
        float m0 = smm[tc], m1 = smm[tc + 256], m2 = smm[tc + 512], m3 = smm[tc + 768];
        float M = fmaxf(fmaxf(m0, m1), fmaxf(m2, m3));
        float S = sms[tc] * __expf(m0 - M) + sms[tc + 256] * __expf(m1 - M) +
                  sms[tc + 512] * __expf(m2 - M) + sms[tc + 768] * __expf(m3 - M);
        part[h * DIM + j] = make_float2(M, S);
    }
}

__global__ __launch_bounds__(256) void col_combine(const float2* __restrict__ part,
                                                   float* __restrict__ c) {
    int j = blockIdx.x * 256 + threadIdx.x;
    float pm[NRG], ps[NRG];
    float M = -INFINITY;
#pragma unroll
    for (int h = 0; h < NRG; ++h) {
        float2 p = part[h * DIM + j];
        pm[h] = p.x; ps[h] = p.y;
        M = fmaxf(M, p.x);
    }
    float S = 0.0f;
#pragma unroll
    for (int h = 0; h < NRG; ++h) S += ps[h] * __expf(pm[h] - M);
    c[j] = M + __logf(S);
}

__global__ __launch_bounds__(256) void final_exp(float* __restrict__ L0,
                                                 const float* __restrict__ r,
                                                 const float* __restrict__ c) {
    const float4* c4 = (const float4*)c;
    float4* a4 = (float4*)L0;
    int idx = blockIdx.x * blockDim.x + threadIdx.x;
    int stride = gridDim.x * blockDim.x;
    for (int p = idx; p < DIM * DIM / 4; p += stride) {
        int i  = p >> 10;
        int j4 = p & 1023;
        float4 a = a4[p];
        float rrv = r[i];
        float4 ccv = c4[j4];
        a.x = __expf(a.x - rrv - ccv.x);
        a.y = __expf(a.y - rrv - ccv.y);
        a.z = __expf(a.z - rrv - ccv.z);
        a.w = __expf(a.w - rrv - ccv.w);
        a4[p] = a;
    }
}

// ====================================== launch ===================================
extern "C" void kernel_launch(void* const* d_in, const int* in_sizes, int n_in,
                              void* d_out, int out_size, void* d_ws, size_t ws_size,
                              hipStream_t stream) {
    const float* logits = (const float*)d_in[0];
    const float* noise  = (const float*)d_in[1];
    float* out = (float*)d_out;
    float* cg  = (float*)d_ws;                          // 16 KiB global c
    unsigned* bar = (unsigned*)((char*)d_ws + 16384);   // barrier state

    zero_bar<<<1, 256, 0, stream>>>(bar);
    void* args[] = { (void*)&logits, (void*)&noise, (void*)&out, (void*)&cg, (void*)&bar };
    hipError_t err = hipLaunchCooperativeKernel((const void*)sinkhorn_lds,
                                                dim3(NB), dim3(NT), args, 0, stream);
    if (err != hipSuccess) {
        // fallback: round-1 multi-kernel pipeline (known-good)
        float* ws = (float*)d_ws;
        float*  r    = ws;
        float*  cf   = ws + DIM;
        float2* part = (float2*)(ws + 2 * DIM);
        init_k<<<4096, 256, 0, stream>>>(logits, noise, out, cf);
        for (int t = 0; t < NITER; ++t) {
            row_lse<<<DIM, 256, 0, stream>>>(out, cf, r);
            col_partial<<<dim3(16, 16), 1024, 0, stream>>>(out, r, part);
            col_combine<<<16, 256, 0, stream>>>(part, cf);
        }
        final_exp<<<4096, 256, 0, stream>>>(out, r, cf);
    }
}

// Round 5
// 591.182 us; speedup vs baseline: 5.2116x; 2.7112x over previous
//
#include <hip/hip_runtime.h>
#include <math.h>

#define DIM   4096
#define NITER 20
#define EPSF  1e-10f
#define NB    256
#define NT    1024
#define RPB   16           // rows per block
#define NRG   16           // fallback path

typedef __attribute__((ext_vector_type(4))) _Float16 half4;

// ---------- MALL-coherent scalar access (no L2 maintenance needed) ----------
__device__ __forceinline__ void st_co(float* p, float v) {
    __hip_atomic_store(p, v, __ATOMIC_RELAXED, __HIP_MEMORY_SCOPE_AGENT);
}
__device__ __forceinline__ float ld_co(const float* p) {
    return __hip_atomic_load(p, __ATOMIC_RELAXED, __HIP_MEMORY_SCOPE_AGENT);
}

// ================= monotonic grid barrier — ALL RELAXED, no wbl2/inv ============
// bar layout (64B slots): gen@0, root@16, cnt[g]@32+16g (g<8). Counters never
// reset; barrier `idx` completes when cnt[g]==32*(idx+1), root==8*(idx+1).
// Block->XCD is round-robin (b%8) so each cnt line is contended only intra-XCD.
__device__ __forceinline__ void gridbarrier(unsigned* bar, int b, unsigned idx) {
    __syncthreads();   // drains vmcnt: all block's data stores are MALL-acked
    if (threadIdx.x == 0) {
        unsigned* gen  = bar;
        unsigned* root = bar + 16;
        unsigned* cnt  = bar + 32 + 16 * (b & 7);
        unsigned a = __hip_atomic_fetch_add(cnt, 1u, __ATOMIC_RELAXED, __HIP_MEMORY_SCOPE_AGENT);
        if (a == 32u * (idx + 1u) - 1u) {
            unsigned a2 = __hip_atomic_fetch_add(root, 1u, __ATOMIC_RELAXED, __HIP_MEMORY_SCOPE_AGENT);
            if (a2 == 8u * (idx + 1u) - 1u) {
                __hip_atomic_fetch_add(gen, 1u, __ATOMIC_RELAXED, __HIP_MEMORY_SCOPE_AGENT);
            }
        }
        while (__hip_atomic_load(gen, __ATOMIC_RELAXED, __HIP_MEMORY_SCOPE_AGENT) < idx + 1u)
            __builtin_amdgcn_s_sleep(1);
    }
    __syncthreads();
}

__global__ void zero_bar(unsigned* bar) {
    if (threadIdx.x < 256) bar[threadIdx.x] = 0u;
}

// ============ persistent Sinkhorn: matrix lives in LDS as fp16 ===================
__global__ __launch_bounds__(NT, 4) void sinkhorn_lds(
        const float* __restrict__ logits, const float* __restrict__ noise,
        float* __restrict__ out, float* __restrict__ cg, unsigned* __restrict__ bar) {
    __shared__ _Float16 lm[RPB][DIM];   // 128 KiB: block's 16 rows of L0
    __shared__ float    lc[DIM];        //  16 KiB: local fp32 copy of c
    __shared__ float    rbc[RPB];       // row potentials

    const int t = threadIdx.x;
    const int b = blockIdx.x;
    const int wave = t >> 6, lane = t & 63;
    const int g0 = b * RPB;
    float* part = out;                  // first 4 MiB of out = partial scratch

    // ---- init: L0 = logits + gumbel(noise) -> fp16 in LDS (HBM read once) ----
#pragma unroll
    for (int r = 0; r < RPB; ++r) {
        const float4 l = *(const float4*)(logits + (size_t)(g0 + r) * DIM + 4 * t);
        const float4 u = *(const float4*)(noise  + (size_t)(g0 + r) * DIM + 4 * t);
        half4 h;
        h.x = (_Float16)(l.x - __logf(-__logf(u.x + EPSF) + EPSF));
        h.y = (_Float16)(l.y - __logf(-__logf(u.y + EPSF) + EPSF));
        h.z = (_Float16)(l.z - __logf(-__logf(u.z + EPSF) + EPSF));
        h.w = (_Float16)(l.w - __logf(-__logf(u.w + EPSF) + EPSF));
        *(half4*)&lm[r][4 * t] = h;
    }
    *(float4*)&lc[4 * t] = make_float4(0.f, 0.f, 0.f, 0.f);
    __syncthreads();

    for (int it = 0; it < NITER; ++it) {
        // ---------- row LSE: wave w <-> row w, exact two-pass, shfl butterfly ----
        {
            float m = -1e30f;
#pragma unroll
            for (int k = 0; k < 16; ++k) {
                const int col = (k * 64 + lane) * 4;
                const half4  h  = *(const half4*)&lm[wave][col];
                const float4 c4 = *(const float4*)&lc[col];
                m = fmaxf(m, fmaxf(fmaxf((float)h.x - c4.x, (float)h.y - c4.y),
                                   fmaxf((float)h.z - c4.z, (float)h.w - c4.w)));
            }
#pragma unroll
            for (int o = 1; o < 64; o <<= 1) m = fmaxf(m, __shfl_xor(m, o, 64));
            float s = 0.f;
#pragma unroll
            for (int k = 0; k < 16; ++k) {
                const int col = (k * 64 + lane) * 4;
                const half4  h  = *(const half4*)&lm[wave][col];
                const float4 c4 = *(const float4*)&lc[col];
                s += __expf((float)h.x - c4.x - m) + __expf((float)h.y - c4.y - m)
                   + __expf((float)h.z - c4.z - m) + __expf((float)h.w - c4.w - m);
            }
#pragma unroll
            for (int o = 1; o < 64; o <<= 1) s += __shfl_xor(s, o, 64);
            if (lane == 0) rbc[wave] = m + __logf(s);
        }
        __syncthreads();

        // ---------- col partial LSE: thread t <-> cols 4t..4t+3 over 16 rows ----
        {
            float4 mx = make_float4(-1e30f, -1e30f, -1e30f, -1e30f);
#pragma unroll
            for (int r2 = 0; r2 < RPB; ++r2) {
                const half4 h = *(const half4*)&lm[r2][4 * t];
                const float rr = rbc[r2];
                mx.x = fmaxf(mx.x, (float)h.x - rr);
                mx.y = fmaxf(mx.y, (float)h.y - rr);
                mx.z = fmaxf(mx.z, (float)h.z - rr);
                mx.w = fmaxf(mx.w, (float)h.w - rr);
            }
            float4 sm = make_float4(0.f, 0.f, 0.f, 0.f);
#pragma unroll
            for (int r2 = 0; r2 < RPB; ++r2) {
                const half4 h = *(const half4*)&lm[r2][4 * t];
                const float rr = rbc[r2];
                sm.x += __expf((float)h.x - rr - mx.x);
                sm.y += __expf((float)h.y - rr - mx.y);
                sm.z += __expf((float)h.z - rr - mx.z);
                sm.w += __expf((float)h.w - rr - mx.w);
            }
            float* pp = part + (size_t)b * DIM + 4 * t;
            st_co(pp + 0, mx.x + __logf(sm.x));
            st_co(pp + 1, mx.y + __logf(sm.y));
            st_co(pp + 2, mx.z + __logf(sm.z));
            st_co(pp + 3, mx.w + __logf(sm.w));
        }

        gridbarrier(bar, b, 2u * it);

        // ---------- combine: wave w -> c[16b + w] over 256 block partials ----
        {
            const int jj = g0 + wave;
            const float p0 = ld_co(part + (size_t)(lane      ) * DIM + jj);
            const float p1 = ld_co(part + (size_t)(lane +  64) * DIM + jj);
            const float p2 = ld_co(part + (size_t)(lane + 128) * DIM + jj);
            const float p3 = ld_co(part + (size_t)(lane + 192) * DIM + jj);
            float m = fmaxf(fmaxf(p0, p1), fmaxf(p2, p3));
#pragma unroll
            for (int o = 1; o < 64; o <<= 1) m = fmaxf(m, __shfl_xor(m, o, 64));
            float s = __expf(p0 - m) + __expf(p1 - m) + __expf(p2 - m) + __expf(p3 - m);
#pragma unroll
            for (int o = 1; o < 64; o <<= 1) s += __shfl_xor(s, o, 64);
            if (lane == 0) st_co(cg + jj, m + __logf(s));
        }

        gridbarrier(bar, b, 2u * it + 1u);

        // ---------- refresh local c copy (MALL-coherent reads) ----------
        lc[4 * t + 0] = ld_co(cg + 4 * t + 0);
        lc[4 * t + 1] = ld_co(cg + 4 * t + 1);
        lc[4 * t + 2] = ld_co(cg + 4 * t + 2);
        lc[4 * t + 3] = ld_co(cg + 4 * t + 3);
        __syncthreads();
    }

    // ---------- final: out = exp(L0 - r - c) ----------
    const float4 c4f = *(const float4*)&lc[4 * t];
#pragma unroll
    for (int r = 0; r < RPB; ++r) {
        const half4 h = *(const half4*)&lm[r][4 * t];
        const float rr = rbc[r];
        float4 o;
        o.x = __expf((float)h.x - rr - c4f.x);
        o.y = __expf((float)h.y - rr - c4f.y);
        o.z = __expf((float)h.z - rr - c4f.z);
        o.w = __expf((float)h.w - rr - c4f.w);
        *(float4*)(out + (size_t)(g0 + r) * DIM + 4 * t) = o;
    }
}

// =================== fallback pipeline (round-1, known-good 769 us) ==============
__device__ __forceinline__ float waveMaxF(float v) {
#pragma unroll
    for (int o = 32; o > 0; o >>= 1) v = fmaxf(v, __shfl_down(v, o, 64));
    return v;
}
__device__ __forceinline__ float waveSumF(float v) {
#pragma unroll
    for (int o = 32; o > 0; o >>= 1) v += __shfl_down(v, o, 64);
    return v;
}

__global__ __launch_bounds__(256) void init_k(const float* __restrict__ logits,
                                              const float* __restrict__ noise,
                                              float* __restrict__ L0,
                                              float* __restrict__ c) {
    int idx = blockIdx.x * blockDim.x + threadIdx.x;
    int stride = gridDim.x * blockDim.x;
    const float4* l4 = (const float4*)logits;
    const float4* n4 = (const float4*)noise;
    float4* o4 = (float4*)L0;
    for (int p = idx; p < DIM * DIM / 4; p += stride) {
        float4 l = l4[p];
        float4 u = n4[p];
        float4 o;
        o.x = l.x - __logf(-__logf(u.x + EPSF) + EPSF);
        o.y = l.y - __logf(-__logf(u.y + EPSF) + EPSF);
        o.z = l.z - __logf(-__logf(u.z + EPSF) + EPSF);
        o.w = l.w - __logf(-__logf(u.w + EPSF) + EPSF);
        o4[p] = o;
    }
    if (idx < DIM) c[idx] = 0.0f;
}

__global__ __launch_bounds__(256) void row_lse(const float* __restrict__ L0,
                                               const float* __restrict__ c,
                                               float* __restrict__ r) {
    __shared__ float red[8];
    const int row = blockIdx.x;
    const int t = threadIdx.x;
    const float4* a4 = (const float4*)(L0 + (size_t)row * DIM);
    const float4* c4 = (const float4*)c;
    float v[16];
    float m = -INFINITY;
#pragma unroll
    for (int k = 0; k < 4; ++k) {
        float4 a  = a4[t + k * 256];
        float4 cc = c4[t + k * 256];
        v[4 * k + 0] = a.x - cc.x;
        v[4 * k + 1] = a.y - cc.y;
        v[4 * k + 2] = a.z - cc.z;
        v[4 * k + 3] = a.w - cc.w;
        m = fmaxf(m, fmaxf(fmaxf(v[4 * k], v[4 * k + 1]), fmaxf(v[4 * k + 2], v[4 * k + 3])));
    }
    m = waveMaxF(m);
    const int lane = t & 63, wid = t >> 6;
    if (lane == 0) red[wid] = m;
    __syncthreads();
    const float bm = fmaxf(fmaxf(red[0], red[1]), fmaxf(red[2], red[3]));
    float s = 0.0f;
#pragma unroll
    for (int q = 0; q < 16; ++q) s += __expf(v[q] - bm);
    s = waveSumF(s);
    if (lane == 0) red[4 + wid] = s;
    __syncthreads();
    if (t == 0) r[row] = bm + __logf(red[4] + red[5] + red[6] + red[7]);
}

__global__ __launch_bounds__(1024) void col_partial(const float* __restrict__ L0,
                                                    const float* __restrict__ r,
                                                    float2* __restrict__ part) {
    __shared__ float sr[256];
    __shared__ float smm[1024];
    __shared__ float sms[1024];
    const int g = blockIdx.x, h = blockIdx.y;
    const int tc = threadIdx.x & 255;
    const int ln = threadIdx.x >> 8;
    if (threadIdx.x < 256) sr[threadIdx.x] = r[h * 256 + threadIdx.x];
    __syncthreads();
    const int j = g * 256 + tc;
    float m = -INFINITY, s = 0.0f;
#pragma unroll 4
    for (int k = 0; k < 64; ++k) {
        int ii = k * 4 + ln;
        float v = L0[(size_t)(h * 256 + ii) * DIM + j] - sr[ii];
        float nm = fmaxf(m, v);
        s = s * __expf(m - nm) + __expf(v - nm);
        m = nm;
    }
    smm[threadIdx.x] = m;
    sms[threadIdx.x] = s;
    __syncthreads();
    if (threadIdx.x < 256) {
        float m0 = smm[tc], m1 = smm[tc + 256], m2 = smm[tc + 512], m3 = smm[tc + 768];
        float M = fmaxf(fmaxf(m0, m1), fmaxf(m2, m3));
        float S = sms[tc] * __expf(m0 - M) + sms[tc + 256] * __expf(m1 - M) +
                  sms[tc + 512] * __expf(m2 - M) + sms[tc + 768] * __expf(m3 - M);
        part[h * DIM + j] = make_float2(M, S);
    }
}

__global__ __launch_bounds__(256) void col_combine(const float2* __restrict__ part,
                                                   float* __restrict__ c) {
    int j = blockIdx.x * 256 + threadIdx.x;
    float pm[NRG], ps[NRG];
    float M = -INFINITY;
#pragma unroll
    for (int h = 0; h < NRG; ++h) {
        float2 p = part[h * DIM + j];
        pm[h] = p.x; ps[h] = p.y;
        M = fmaxf(M, p.x);
    }
    float S = 0.0f;
#pragma unroll
    for (int h = 0; h < NRG; ++h) S += ps[h] * __expf(pm[h] - M);
    c[j] = M + __logf(S);
}

__global__ __launch_bounds__(256) void final_exp(float* __restrict__ L0,
                                                 const float* __restrict__ r,
                                                 const float* __restrict__ c) {
    const float4* c4 = (const float4*)c;
    float4* a4 = (float4*)L0;
    int idx = blockIdx.x * blockDim.x + threadIdx.x;
    int stride = gridDim.x * blockDim.x;
    for (int p = idx; p < DIM * DIM / 4; p += stride) {
        int i  = p >> 10;
        int j4 = p & 1023;
        float4 a = a4[p];
        float rrv = r[i];
        float4 ccv = c4[j4];
        a.x = __expf(a.x - rrv - ccv.x);
        a.y = __expf(a.y - rrv - ccv.y);
        a.z = __expf(a.z - rrv - ccv.z);
        a.w = __expf(a.w - rrv - ccv.w);
        a4[p] = a;
    }
}

// ====================================== launch ===================================
extern "C" void kernel_launch(void* const* d_in, const int* in_sizes, int n_in,
                              void* d_out, int out_size, void* d_ws, size_t ws_size,
                              hipStream_t stream) {
    const float* logits = (const float*)d_in[0];
    const float* noise  = (const float*)d_in[1];
    float* out = (float*)d_out;
    float* cg  = (float*)d_ws;                          // 16 KiB global c
    unsigned* bar = (unsigned*)((char*)d_ws + 16384);   // barrier state

    zero_bar<<<1, 256, 0, stream>>>(bar);
    void* args[] = { (void*)&logits, (void*)&noise, (void*)&out, (void*)&cg, (void*)&bar };
    hipError_t err = hipLaunchCooperativeKernel((const void*)sinkhorn_lds,
                                                dim3(NB), dim3(NT), args, 0, stream);
    if (err != hipSuccess) {
        // fallback: round-1 multi-kernel pipeline (known-good)
        float* ws = (float*)d_ws;
        float*  r    = ws;
        float*  cf   = ws + DIM;
        float2* part = (float2*)(ws + 2 * DIM);
        init_k<<<4096, 256, 0, stream>>>(logits, noise, out, cf);
        for (int t = 0; t < NITER; ++t) {
            row_lse<<<DIM, 256, 0, stream>>>(out, cf, r);
            col_partial<<<dim3(16, 16), 1024, 0, stream>>>(out, r, part);
            col_combine<<<16, 256, 0, stream>>>(part, cf);
        }
        final_exp<<<4096, 256, 0, stream>>>(out, r, cf);
    }
}